// Round 4
// baseline (189.911 us; speedup 1.0000x reference)
//
#include <hip/hip_runtime.h>
#include <math.h>

#define BATCH 32768
#define NCLS  1000
#define NVEC  250            // 1000 / 4 float4s per row
#define SCALE 30.0f
#define K_LOG2E 43.28085122666891f   // 30 * log2(e)
#define LN2 0.69314718055994531f
#define RPW 4                        // rows per wave
#define NBLOCKS (BATCH / (4 * RPW))  // 2048 blocks, 4 waves each

__device__ __forceinline__ void load_row(const float4* __restrict__ rowv, int lane,
                                         float4 w[4]) {
    w[0] = rowv[lane];
    w[1] = rowv[lane + 64];
    w[2] = rowv[lane + 128];
    if (lane < NVEC - 192)  // lanes 0..57 valid for the 4th vector
        w[3] = rowv[lane + 192];
    else
        w[3] = make_float4(-INFINITY, -INFINITY, -INFINITY, -INFINITY);
}

__device__ __forceinline__ float row_nll(const float4 w[4], int lane, int t, float mt) {
    float s[16];
    float st = -INFINITY;            // owner lane captures x_t - m_t
    #pragma unroll
    for (int j = 0; j < 4; ++j) {
        float4 v = w[j];
        const int base = 4 * (lane + 64 * j);
        if (base + 0 == t) { v.x -= mt; st = v.x; }
        if (base + 1 == t) { v.y -= mt; st = v.y; }
        if (base + 2 == t) { v.z -= mt; st = v.z; }
        if (base + 3 == t) { v.w -= mt; st = v.w; }
        s[4*j + 0] = v.x; s[4*j + 1] = v.y;
        s[4*j + 2] = v.z; s[4*j + 3] = v.w;
    }
    float m = s[0];
    #pragma unroll
    for (int k = 1; k < 16; ++k) m = fmaxf(m, s[k]);
    #pragma unroll
    for (int off = 1; off < 64; off <<= 1) {
        m  = fmaxf(m,  __shfl_xor(m,  off));
        st = fmaxf(st, __shfl_xor(st, off));
    }
    float l = 0.0f;
    #pragma unroll
    for (int k = 0; k < 16; ++k)
        l += __builtin_amdgcn_exp2f(K_LOG2E * (s[k] - m));
    #pragma unroll
    for (int off = 1; off < 64; off <<= 1)
        l += __shfl_xor(l, off);
    return SCALE * (m - st) + LN2 * __builtin_amdgcn_logf(l);
}

__global__ __launch_bounds__(256) void ldam_kernel(
    const float* __restrict__ logits,
    const float* __restrict__ margins,
    const int*   __restrict__ targets,
    float*       __restrict__ partials)
{
    const int wave = threadIdx.x >> 6;
    const int lane = threadIdx.x & 63;
    const int wid  = blockIdx.x * 4 + wave;   // 0..8191
    const int row0 = wid * RPW;               // 4 consecutive rows per wave

    // Hoist all per-row scalars: one int4 for targets, 4 margin gathers.
    const int4 tv = *(const int4*)(targets + row0);
    const int   ts[4]  = {tv.x, tv.y, tv.z, tv.w};
    const float mts[4] = {margins[tv.x], margins[tv.y], margins[tv.z], margins[tv.w]};

    const float4* rowv = (const float4*)(logits + (size_t)row0 * NCLS);

    float4 cur[4], nxt[4];
    load_row(rowv, lane, cur);

    float acc = 0.0f;
    #pragma unroll
    for (int r = 0; r < RPW; ++r) {
        // Prefetch next row before this row's dependent reduce chain.
        if (r + 1 < RPW)
            load_row(rowv + (size_t)(r + 1) * NVEC, lane, nxt);
        acc += row_nll(cur, lane, ts[r], mts[r]);
        #pragma unroll
        for (int j = 0; j < 4; ++j) cur[j] = nxt[j];
    }

    __shared__ float part[4];
    if (lane == 0) part[wave] = acc;
    __syncthreads();
    if (threadIdx.x == 0)
        partials[blockIdx.x] = part[0] + part[1] + part[2] + part[3];
}

// Single-block reduction of NBLOCKS partials -> mean in out[0].
__global__ __launch_bounds__(256) void ldam_reduce_kernel(
    const float* __restrict__ partials,
    float*       __restrict__ out)
{
    const int tid  = threadIdx.x;
    const int lane = tid & 63;
    const int wave = tid >> 6;

    // 2048 floats = 512 float4s; 256 threads * 2 float4 each.
    const float4* pv = (const float4*)partials;
    float sum = 0.0f;
    #pragma unroll
    for (int j = 0; j < 2; ++j) {
        const float4 v = pv[tid + 256 * j];
        sum += (v.x + v.y) + (v.z + v.w);
    }

    #pragma unroll
    for (int off = 1; off < 64; off <<= 1)
        sum += __shfl_xor(sum, off);

    __shared__ float ws_[4];
    if (lane == 0) ws_[wave] = sum;
    __syncthreads();
    if (tid == 0)
        out[0] = (ws_[0] + ws_[1] + ws_[2] + ws_[3]) * (1.0f / (float)BATCH);
}

extern "C" void kernel_launch(void* const* d_in, const int* in_sizes, int n_in,
                              void* d_out, int out_size, void* d_ws, size_t ws_size,
                              hipStream_t stream) {
    const float* logits  = (const float*)d_in[0];
    const float* margins = (const float*)d_in[1];
    const int*   targets = (const int*)d_in[2];
    float* out      = (float*)d_out;
    float* partials = (float*)d_ws;

    ldam_kernel<<<NBLOCKS, 256, 0, stream>>>(logits, margins, targets, partials);
    ldam_reduce_kernel<<<1, 256, 0, stream>>>(partials, out);
}

// Round 5
// 180.302 us; speedup vs baseline: 1.0533x; 1.0533x over previous
//
#include <hip/hip_runtime.h>
#include <math.h>

#define BATCH 32768
#define NCLS  1000
#define NVEC  250            // 1000 / 4 float4s per row
#define SCALE 30.0f
#define K_LOG2E 43.28085122666891f   // 30 * log2(e)
#define LN2 0.69314718055994531f
#define NBLOCKS (BATCH / 4)  // 8192 blocks, 4 rows (waves) per block

typedef float f4 __attribute__((ext_vector_type(4)));

__global__ __launch_bounds__(256) void ldam_kernel(
    const float* __restrict__ logits,
    const float* __restrict__ margins,
    const int*   __restrict__ targets,
    float*       __restrict__ partials)
{
    const int wave = threadIdx.x >> 6;      // 0..3
    const int lane = threadIdx.x & 63;
    const int row  = blockIdx.x * 4 + wave; // one wave per row

    const int   t  = targets[row];          // wave-uniform -> scalar load
    const float mt = margins[t];
    const f4* rowv = (const f4*)(logits + (size_t)row * NCLS);

    // Non-temporal float4 loads: stream-once data, bypass cache allocate.
    f4 w[4];
    w[0] = __builtin_nontemporal_load(rowv + lane);
    w[1] = __builtin_nontemporal_load(rowv + lane + 64);
    w[2] = __builtin_nontemporal_load(rowv + lane + 128);
    if (lane < NVEC - 192) {                // lanes 0..57 valid for 4th vector
        w[3] = __builtin_nontemporal_load(rowv + lane + 192);
    } else {
        w[3] = (f4){-INFINITY, -INFINITY, -INFINITY, -INFINITY};
    }

    // Apply margin at target component; capture target score in-register.
    float s[16];
    float st = -INFINITY;                   // owner lane gets x_t - m_t
    #pragma unroll
    for (int j = 0; j < 4; ++j) {
        f4 v = w[j];
        const int base = 4 * (lane + 64 * j);
        if (base + 0 == t) { v.x -= mt; st = v.x; }
        if (base + 1 == t) { v.y -= mt; st = v.y; }
        if (base + 2 == t) { v.z -= mt; st = v.z; }
        if (base + 3 == t) { v.w -= mt; st = v.w; }
        s[4*j + 0] = v.x; s[4*j + 1] = v.y;
        s[4*j + 2] = v.z; s[4*j + 3] = v.w;
    }

    // Per-lane max, then wave-wide max butterfly for both m and st.
    float m = s[0];
    #pragma unroll
    for (int k = 1; k < 16; ++k) m = fmaxf(m, s[k]);
    #pragma unroll
    for (int off = 1; off < 64; off <<= 1) {
        m  = fmaxf(m,  __shfl_xor(m,  off));
        st = fmaxf(st, __shfl_xor(st, off));
    }

    // Sum of 2^(K*(s-m)); padding lanes contribute exp2(-inf) = 0.
    float l = 0.0f;
    #pragma unroll
    for (int k = 0; k < 16; ++k)
        l += __builtin_amdgcn_exp2f(K_LOG2E * (s[k] - m));
    #pragma unroll
    for (int off = 1; off < 64; off <<= 1)
        l += __shfl_xor(l, off);

    // nll = logsumexp(30*s) - 30*st = 30*(m - st) + ln2 * log2(l)
    const float nll = SCALE * (m - st) + LN2 * __builtin_amdgcn_logf(l);

    __shared__ float partial[4];
    if (lane == 0) partial[wave] = nll;
    __syncthreads();
    if (threadIdx.x == 0)
        partials[blockIdx.x] = partial[0] + partial[1] + partial[2] + partial[3];
}

// Single-block reduction of NBLOCKS partials -> mean in out[0].
__global__ __launch_bounds__(256) void ldam_reduce_kernel(
    const float* __restrict__ partials,
    float*       __restrict__ out)
{
    const int tid  = threadIdx.x;
    const int lane = tid & 63;
    const int wave = tid >> 6;

    // 8192 floats = 2048 float4s; 256 threads * 8 float4 each.
    const float4* pv = (const float4*)partials;
    float sum = 0.0f;
    #pragma unroll
    for (int j = 0; j < 8; ++j) {
        const float4 v = pv[tid + 256 * j];
        sum += (v.x + v.y) + (v.z + v.w);
    }

    #pragma unroll
    for (int off = 1; off < 64; off <<= 1)
        sum += __shfl_xor(sum, off);

    __shared__ float ws_[4];
    if (lane == 0) ws_[wave] = sum;
    __syncthreads();
    if (tid == 0)
        out[0] = (ws_[0] + ws_[1] + ws_[2] + ws_[3]) * (1.0f / (float)BATCH);
}

extern "C" void kernel_launch(void* const* d_in, const int* in_sizes, int n_in,
                              void* d_out, int out_size, void* d_ws, size_t ws_size,
                              hipStream_t stream) {
    const float* logits  = (const float*)d_in[0];
    const float* margins = (const float*)d_in[1];
    const int*   targets = (const int*)d_in[2];
    float* out      = (float*)d_out;
    float* partials = (float*)d_ws;

    ldam_kernel<<<NBLOCKS, 256, 0, stream>>>(logits, margins, targets, partials);
    ldam_reduce_kernel<<<1, 256, 0, stream>>>(partials, out);
}

// Round 6
// 176.323 us; speedup vs baseline: 1.0771x; 1.0226x over previous
//
#include <hip/hip_runtime.h>
#include <math.h>

#define BATCH 32768
#define NCLS  1000
#define NVEC  250            // 1000 / 4 float4s per row
#define SCALE 30.0f
#define K_LOG2E 43.28085122666891f   // 30 * log2(e)
#define LN2 0.69314718055994531f
#define NBLOCKS (BATCH / 8)  // 4096 blocks: 4 waves x 2 rows per wave

typedef float f4 __attribute__((ext_vector_type(4)));

__device__ __forceinline__ void load_row_nt(const f4* __restrict__ rowv, int lane,
                                            f4 w[4]) {
    w[0] = __builtin_nontemporal_load(rowv + lane);
    w[1] = __builtin_nontemporal_load(rowv + lane + 64);
    w[2] = __builtin_nontemporal_load(rowv + lane + 128);
    if (lane < NVEC - 192)
        w[3] = __builtin_nontemporal_load(rowv + lane + 192);
    else
        w[3] = (f4){-INFINITY, -INFINITY, -INFINITY, -INFINITY};
}

__global__ __launch_bounds__(256) void ldam_kernel(
    const float* __restrict__ logits,
    const float* __restrict__ margins,
    const int*   __restrict__ targets,
    float*       __restrict__ partials)
{
    const int wave = threadIdx.x >> 6;        // 0..3
    const int lane = threadIdx.x & 63;
    const int row0 = (blockIdx.x * 4 + wave) * 2;  // 2 rows per wave

    const int2  tv = *(const int2*)(targets + row0);
    const int   t0 = tv.x, t1 = tv.y;
    const float mt0 = margins[t0], mt1 = margins[t1];

    const f4* rv0 = (const f4*)(logits + (size_t)row0 * NCLS);
    const f4* rv1 = rv0 + NVEC;

    // 8 nt loads in flight before any use.
    f4 a[4], b[4];
    load_row_nt(rv0, lane, a);
    load_row_nt(rv1, lane, b);

    // Apply margin at target component; owner lane keeps the target score.
    float s0[16], s1[16];
    float st0 = 0.0f, st1 = 0.0f;
    #pragma unroll
    for (int j = 0; j < 4; ++j) {
        f4 v = a[j];
        const int base = 4 * (lane + 64 * j);
        if (base + 0 == t0) { v.x -= mt0; st0 = v.x; }
        if (base + 1 == t0) { v.y -= mt0; st0 = v.y; }
        if (base + 2 == t0) { v.z -= mt0; st0 = v.z; }
        if (base + 3 == t0) { v.w -= mt0; st0 = v.w; }
        s0[4*j+0] = v.x; s0[4*j+1] = v.y; s0[4*j+2] = v.z; s0[4*j+3] = v.w;
    }
    #pragma unroll
    for (int j = 0; j < 4; ++j) {
        f4 v = b[j];
        const int base = 4 * (lane + 64 * j);
        if (base + 0 == t1) { v.x -= mt1; st1 = v.x; }
        if (base + 1 == t1) { v.y -= mt1; st1 = v.y; }
        if (base + 2 == t1) { v.z -= mt1; st1 = v.z; }
        if (base + 3 == t1) { v.w -= mt1; st1 = v.w; }
        s1[4*j+0] = v.x; s1[4*j+1] = v.y; s1[4*j+2] = v.z; s1[4*j+3] = v.w;
    }

    // Owner lane of the target's float4 is wave-uniform: one shfl broadcast
    // replaces a 6-step max butterfly.
    st0 = __shfl(st0, (t0 >> 2) & 63);
    st1 = __shfl(st1, (t1 >> 2) & 63);

    // Two independent max chains, interleaved for ILP.
    float m0 = s0[0], m1 = s1[0];
    #pragma unroll
    for (int k = 1; k < 16; ++k) { m0 = fmaxf(m0, s0[k]); m1 = fmaxf(m1, s1[k]); }
    #pragma unroll
    for (int off = 1; off < 64; off <<= 1) {
        m0 = fmaxf(m0, __shfl_xor(m0, off));
        m1 = fmaxf(m1, __shfl_xor(m1, off));
    }

    // exp sums (padding lanes contribute exp2(-inf) = 0), interleaved.
    float l0 = 0.0f, l1 = 0.0f;
    #pragma unroll
    for (int k = 0; k < 16; ++k) {
        l0 += __builtin_amdgcn_exp2f(K_LOG2E * (s0[k] - m0));
        l1 += __builtin_amdgcn_exp2f(K_LOG2E * (s1[k] - m1));
    }
    #pragma unroll
    for (int off = 1; off < 64; off <<= 1) {
        l0 += __shfl_xor(l0, off);
        l1 += __shfl_xor(l1, off);
    }

    const float nll = SCALE * ((m0 - st0) + (m1 - st1))
                    + LN2 * (__builtin_amdgcn_logf(l0) + __builtin_amdgcn_logf(l1));

    __shared__ float partial[4];
    if (lane == 0) partial[wave] = nll;
    __syncthreads();
    if (threadIdx.x == 0)
        partials[blockIdx.x] = partial[0] + partial[1] + partial[2] + partial[3];
}

// Single-block reduction of NBLOCKS partials -> mean in out[0].
__global__ __launch_bounds__(256) void ldam_reduce_kernel(
    const float* __restrict__ partials,
    float*       __restrict__ out)
{
    const int tid  = threadIdx.x;
    const int lane = tid & 63;
    const int wave = tid >> 6;

    // 4096 floats = 1024 float4s; 256 threads * 4 float4 each.
    const float4* pv = (const float4*)partials;
    float sum = 0.0f;
    #pragma unroll
    for (int j = 0; j < 4; ++j) {
        const float4 v = pv[tid + 256 * j];
        sum += (v.x + v.y) + (v.z + v.w);
    }

    #pragma unroll
    for (int off = 1; off < 64; off <<= 1)
        sum += __shfl_xor(sum, off);

    __shared__ float ws_[4];
    if (lane == 0) ws_[wave] = sum;
    __syncthreads();
    if (tid == 0)
        out[0] = (ws_[0] + ws_[1] + ws_[2] + ws_[3]) * (1.0f / (float)BATCH);
}

extern "C" void kernel_launch(void* const* d_in, const int* in_sizes, int n_in,
                              void* d_out, int out_size, void* d_ws, size_t ws_size,
                              hipStream_t stream) {
    const float* logits  = (const float*)d_in[0];
    const float* margins = (const float*)d_in[1];
    const int*   targets = (const int*)d_in[2];
    float* out      = (float*)d_out;
    float* partials = (float*)d_ws;

    ldam_kernel<<<NBLOCKS, 256, 0, stream>>>(logits, margins, targets, partials);
    ldam_reduce_kernel<<<1, 256, 0, stream>>>(partials, out);
}